// Round 8
// baseline (264.822 us; speedup 1.0000x reference)
//
#include <hip/hip_runtime.h>
#include <math.h>

#define DIM 512
#define INTER 64
#define N_ROUTED 64
#define TOPK 6
#define NTOK 1024            // B*T
#define TTILE 16             // tokens per ffn tile
#define GR 8                 // blocks per routed expert (64*8 = 512)
#define GS 64                // blocks per shared expert (2*64 = 128)
#define CHN (NTOK * TOPK)    // 6144 dense choice entries
#define CHUNK (CHN / 256)    // 24 entries per thread in the list scan

// ---------------------------------------------------------------------------
// Gate (dispatch 1 of 2): 4 tokens per block, 256 blocks.
//  - zeroes its 4 output rows (replaces memset dispatch)
//  - lane holds x[t][lane*4..] and x[t][256+lane*4..] for 4 tokens in regs;
//    wave w computes experts [w*16,w*16+16) for all 4 tokens via coalesced
//    g_w ROW loads + butterfly reduce. g_w traffic: 256x128KB = 32 MB (L2).
//  - wave w then does token w's softmax over 64 experts + iterative top-6
//    argmax on (prob+bias), first-index tie-break (matches lax.top_k).
// ---------------------------------------------------------------------------
__global__ __launch_bounds__(256) void gate_kernel(
    const float* __restrict__ x, const float* __restrict__ g_w,
    const float* __restrict__ gate_bias,
    int* __restrict__ chidx, float* __restrict__ chw,
    float* __restrict__ out) {
  __shared__ float logits[4][N_ROUTED];
  const int t0 = blockIdx.x * 4;
  const int tid = threadIdx.x;
  const int lane = tid & 63;
  const int w = tid >> 6;

  // zero the 4 output rows: 4*512 floats = 512 float4, 2 per thread
  {
    float4* ob = (float4*)(out + (size_t)t0 * DIM);
    ob[tid] = make_float4(0.f, 0.f, 0.f, 0.f);
    ob[tid + 256] = make_float4(0.f, 0.f, 0.f, 0.f);
  }

  float4 xa[4], xb[4];
  #pragma unroll
  for (int t = 0; t < 4; ++t) {
    const float* xr = x + (size_t)(t0 + t) * DIM;
    xa[t] = *(const float4*)(xr + lane * 4);
    xb[t] = *(const float4*)(xr + 256 + lane * 4);
  }

  #pragma unroll 2
  for (int k = 0; k < 16; ++k) {
    const int e = w * 16 + k;
    const float* gr = g_w + (size_t)e * DIM;
    const float4 ga = *(const float4*)(gr + lane * 4);
    const float4 gb = *(const float4*)(gr + 256 + lane * 4);
    float v[4];
    #pragma unroll
    for (int t = 0; t < 4; ++t)
      v[t] = xa[t].x * ga.x + xa[t].y * ga.y + xa[t].z * ga.z + xa[t].w * ga.w
           + xb[t].x * gb.x + xb[t].y * gb.y + xb[t].z * gb.z + xb[t].w * gb.w;
    #pragma unroll
    for (int t = 0; t < 4; ++t) {
      float s = v[t];
      for (int off = 32; off; off >>= 1) s += __shfl_xor(s, off, 64);
      if (lane == 0) logits[t][e] = s;
    }
  }
  __syncthreads();

  // wave w handles token t0+w
  {
    const int t = t0 + w;
    const float a = logits[w][lane];
    float m = a;
    for (int off = 32; off; off >>= 1) m = fmaxf(m, __shfl_xor(m, off, 64));
    const float p = expf(a - m);
    float s = p;
    for (int off = 32; off; off >>= 1) s += __shfl_xor(s, off, 64);
    const float prob = p / s;
    float biased = prob + gate_bias[lane];
    for (int k = 0; k < TOPK; ++k) {
      float v = biased;
      int idx = lane;
      for (int off = 1; off < 64; off <<= 1) {
        const float ov = __shfl_xor(v, off, 64);
        const int oi = __shfl_xor(idx, off, 64);
        if (ov > v || (ov == v && oi < idx)) { v = ov; idx = oi; }
      }
      if (lane == idx) {
        chidx[t * TOPK + k] = lane;
        chw[t * TOPK + k] = prob;      // ROUTE_SCALE == 1.0
        biased = -INFINITY;
      }
    }
  }
}

// ---------------------------------------------------------------------------
// Expert FFN (dispatch 2 of 2): block = (expert, group), XCD-pinned
// (expert r runs only on XCD r%8 via blockIdx&7 round-robin heuristic).
// Routed blocks rebuild their own token sub-list from the dense choices via
// a deterministic block prefix-scan (all GR blocks agree on ranks; block g
// takes ranks == g mod GR). No extra dispatch, no atomics.
// Tile: phase A wave w covers d in [w*128,w*128+128) for all 16 tokens
// (lane = inter unit, weights coalesced); token x rows are read via
// READFIRSTLANE-uniform pointers -> compiler emits s_load_dwordx4 (scalar
// path), cutting phase-A VMEM ops 24->8 per iter and the 64-bit VGPR
// address arithmetic. Cross-wave reduce + silu*h3*route_w -> as_;
// phase B: thread owns output cols (tid, tid+256), coalesced atomicAdd.
// 37.9 KB LDS + launch_bounds(256,4) -> 4 blocks/CU; 2 barriers per tile.
// ---------------------------------------------------------------------------
__global__ __launch_bounds__(256, 4) void ffn_kernel(
    const float* __restrict__ x,
    const float* __restrict__ w1, const float* __restrict__ w2,
    const float* __restrict__ w3,
    const int* __restrict__ chidx, const float* __restrict__ chw,
    float* __restrict__ out) {
  __shared__ float part1[4][TTILE][INTER];   // 16 KB
  __shared__ float part3[4][TTILE][INTER];   // 16 KB
  __shared__ float as_[TTILE][INTER];        // 4 KB
  __shared__ int   lTok[128];
  __shared__ float lW[128];
  __shared__ int   waveTot[4];

  const int tid = threadIdx.x;
  const int lane = tid & 63;
  const int w = tid >> 6;
  const int blk = blockIdx.x;

  int e, m;
  if (blk < N_ROUTED * GR) {
    // ---- routed: deterministic sub-list build ----
    const int c = blk & 7;          // XCD residue
    const int q = blk >> 3;         // 0..63
    const int ei = q >> 3;          // 0..7
    const int g = q & 7;            // group within expert
    const int r = ei * 8 + c;       // routed expert id (r%8 == c)
    e = r + 2;

    if (tid < 128) { lTok[tid] = 0; lW[tid] = 0.f; }

    const int j0 = tid * CHUNK;
    int cntL = 0;
    #pragma unroll
    for (int k = 0; k < CHUNK; ++k)
      cntL += (chidx[j0 + k] == r) ? 1 : 0;

    int incl = cntL;                // wave-inclusive prefix
    for (int off = 1; off < 64; off <<= 1) {
      const int v = __shfl_up(incl, off, 64);
      if (lane >= off) incl += v;
    }
    if (lane == 63) waveTot[w] = incl;
    __syncthreads();

    int waveOff = 0, nTot = 0;
    #pragma unroll
    for (int i = 0; i < 4; ++i) {
      const int v = waveTot[i];
      nTot += v;
      if (i < w) waveOff += v;
    }
    int rank = waveOff + incl - cntL;   // exclusive global rank
    for (int k = 0; k < CHUNK; ++k) {
      const int j = j0 + k;
      if (chidx[j] == r) {
        if ((rank & 7) == g) {
          lTok[rank >> 3] = j / TOPK;
          lW[rank >> 3] = chw[j];
        }
        ++rank;
      }
    }
    m = (nTot > g) ? ((nTot - g + 7) >> 3) : 0;
    __syncthreads();
  } else {
    // ---- shared experts: tokens g, g+64, ..., weight 1 ----
    const int sb = blk - N_ROUTED * GR;   // 0..127
    e = sb >> 6;
    const int g = sb & 63;
    if (tid < 128) {
      lTok[tid] = (tid < 16) ? (g + tid * GS) : 0;
      lW[tid] = (tid < 16) ? 1.0f : 0.f;
    }
    m = 16;
    __syncthreads();
  }

  const float* w1p = w1 + (size_t)e * DIM * INTER + lane;
  const float* w3p = w3 + (size_t)e * DIM * INTER + lane;
  const float* w2e = w2 + (size_t)e * INTER * DIM;
  const int d0 = w * 128;

  for (int base = 0; base < m; base += TTILE) {
    const int mt = min(TTILE, m - base);
    // readfirstlane -> provably wave-uniform token ids -> scalar x loads
    int tk[TTILE];
    #pragma unroll
    for (int t = 0; t < TTILE; ++t)
      tk[t] = __builtin_amdgcn_readfirstlane(lTok[base + t]);
    const float* xr[TTILE];
    #pragma unroll
    for (int t = 0; t < TTILE; ++t)
      xr[t] = x + ((size_t)tk[t] << 9);

    // ---- phase A: wave w covers d in [d0,d0+128) for all 16 tokens ----
    float p1[TTILE], p3[TTILE];
    #pragma unroll
    for (int t = 0; t < TTILE; ++t) { p1[t] = 0.f; p3[t] = 0.f; }
    #pragma unroll 2
    for (int d = d0; d < d0 + 128; d += 4) {
      const float a0 = w1p[(d + 0) << 6];
      const float a1 = w1p[(d + 1) << 6];
      const float a2 = w1p[(d + 2) << 6];
      const float a3 = w1p[(d + 3) << 6];
      const float b0 = w3p[(d + 0) << 6];
      const float b1 = w3p[(d + 1) << 6];
      const float b2 = w3p[(d + 2) << 6];
      const float b3 = w3p[(d + 3) << 6];
      #pragma unroll
      for (int t = 0; t < TTILE; ++t) {
        const float4 xv = *(const float4*)(xr[t] + d);   // scalar s_load
        p1[t] += xv.x * a0 + xv.y * a1 + xv.z * a2 + xv.w * a3;
        p3[t] += xv.x * b0 + xv.y * b1 + xv.z * b2 + xv.w * b3;
      }
    }
    #pragma unroll
    for (int t = 0; t < TTILE; ++t) {
      part1[w][t][lane] = p1[t];
      part3[w][t][lane] = p3[t];
    }
    __syncthreads();

    // ---- reduce quarters + silu * h3 * route_weight -> as_ ----
    #pragma unroll
    for (int k = 0; k < 4; ++k) {
      const int idx = tid + k * 256;
      const int t = idx >> 6, ii = idx & 63;
      const float h1 = part1[0][t][ii] + part1[1][t][ii] +
                       part1[2][t][ii] + part1[3][t][ii];
      const float h3 = part3[0][t][ii] + part3[1][t][ii] +
                       part3[2][t][ii] + part3[3][t][ii];
      as_[t][ii] = (h1 / (1.0f + expf(-h1))) * h3 * lW[base + t];
    }
    __syncthreads();

    // ---- phase B: thread owns output cols tid and tid+256 ----
    // (next tile's post-A barrier protects as_/part: no trailing sync needed)
    float o0[TTILE], o1[TTILE];
    #pragma unroll
    for (int t = 0; t < TTILE; ++t) { o0[t] = 0.f; o1[t] = 0.f; }
    for (int ii = 0; ii < INTER; ii += 4) {
      const float u0 = w2e[(ii + 0) * DIM + tid];
      const float u1 = w2e[(ii + 1) * DIM + tid];
      const float u2 = w2e[(ii + 2) * DIM + tid];
      const float u3 = w2e[(ii + 3) * DIM + tid];
      const float v0 = w2e[(ii + 0) * DIM + tid + 256];
      const float v1 = w2e[(ii + 1) * DIM + tid + 256];
      const float v2 = w2e[(ii + 2) * DIM + tid + 256];
      const float v3 = w2e[(ii + 3) * DIM + tid + 256];
      #pragma unroll
      for (int t = 0; t < TTILE; ++t) {
        const float4 av = *(const float4*)&as_[t][ii];     // LDS broadcast
        o0[t] += av.x * u0 + av.y * u1 + av.z * u2 + av.w * u3;
        o1[t] += av.x * v0 + av.y * v1 + av.z * v2 + av.w * v3;
      }
    }
    for (int t = 0; t < mt; ++t) {
      atomicAdd(&out[(size_t)tk[t] * DIM + tid], o0[t]);
      atomicAdd(&out[(size_t)tk[t] * DIM + tid + 256], o1[t]);
    }
  }
}

extern "C" void kernel_launch(void* const* d_in, const int* in_sizes, int n_in,
                              void* d_out, int out_size, void* d_ws, size_t ws_size,
                              hipStream_t stream) {
  const float* x         = (const float*)d_in[0];
  const float* g_w       = (const float*)d_in[1];
  const float* gate_bias = (const float*)d_in[2];
  const float* w1        = (const float*)d_in[3];
  const float* w2        = (const float*)d_in[4];
  const float* w3        = (const float*)d_in[5];
  float* out = (float*)d_out;

  int*   chidx = (int*)d_ws;                        // 6144 ints
  float* chw   = (float*)((char*)d_ws + CHN * 4);   // 6144 floats

  gate_kernel<<<NTOK / 4, 256, 0, stream>>>(x, g_w, gate_bias, chidx, chw, out);
  ffn_kernel<<<N_ROUTED * GR + 2 * GS, 256, 0, stream>>>(
      x, w1, w2, w3, chidx, chw, out);
}